// Round 1
// baseline (176.308 us; speedup 1.0000x reference)
//
#include <hip/hip_runtime.h>
#include <hip/hip_bf16.h>
#include <math.h>

// Top-8 per row of [B, 8192] fp32, out = sum over rows of (1 - sum(top8)).
// Kernel 1: one block per row -> d_ws[row] = 1 - sum(top8(row))
// Kernel 2: reduce d_ws[0..B) -> d_out[0]

#define C_COLS 8192
#define BLOCK 256
#define K 8

__device__ __forceinline__ void topk_insert(float (&t)[K], float v) {
    // t sorted descending; insert v if it beats the current min (t[7]).
    if (v > t[K - 1]) {
        t[K - 1] = v;
#pragma unroll
        for (int i = K - 1; i >= 1; --i) {
            float a = t[i - 1], b = t[i];
            t[i - 1] = fmaxf(a, b);
            t[i]     = fminf(a, b);
        }
    }
}

// Merge two descending sorted 8-lists, keep top-8 (descending), into a.
// c[k] = max over i+j == k-1 (i,j >= -1, a[-1]=b[-1]=+inf) of min(a[i], b[j])
__device__ __forceinline__ void merge8(float (&a)[K], const float (&b)[K]) {
    float c[K];
#pragma unroll
    for (int k = 0; k < K; ++k) {
        float m = -INFINITY;
#pragma unroll
        for (int i = -1; i <= k; ++i) {
            const int j = k - 1 - i;
            if (j < -1 || j > K - 1 || i > K - 1) continue;
            const float ai = (i == -1) ? INFINITY : a[i];
            const float bj = (j == -1) ? INFINITY : b[j];
            m = fmaxf(m, fminf(ai, bj));
        }
        c[k] = m;
    }
#pragma unroll
    for (int k = 0; k < K; ++k) a[k] = c[k];
}

__global__ __launch_bounds__(BLOCK) void hl_topk_rows(const float* __restrict__ vals,
                                                      float* __restrict__ row_out) {
    const int row = blockIdx.x;
    const int tid = threadIdx.x;

    float t[K];
#pragma unroll
    for (int i = 0; i < K; ++i) t[i] = -INFINITY;

    // 8192 floats = 2048 float4; 256 threads x 8 iters, coalesced.
    const float4* rowp = reinterpret_cast<const float4*>(vals + (size_t)row * C_COLS);
#pragma unroll
    for (int j = 0; j < (C_COLS / 4) / BLOCK; ++j) {
        const float4 v = rowp[j * BLOCK + tid];
        topk_insert(t, v.x);
        topk_insert(t, v.y);
        topk_insert(t, v.z);
        topk_insert(t, v.w);
    }

    // Wave-64 butterfly merge: all lanes end with the wave's top-8 (sorted).
#pragma unroll
    for (int m = 1; m < 64; m <<= 1) {
        float o[K];
#pragma unroll
        for (int i = 0; i < K; ++i) o[i] = __shfl_xor(t[i], m, 64);
        merge8(t, o);
    }

    __shared__ float smem[(BLOCK / 64) * K];
    const int wave = tid >> 6;
    const int lane = tid & 63;
    if (lane == 0) {
#pragma unroll
        for (int i = 0; i < K; ++i) smem[wave * K + i] = t[i];
    }
    __syncthreads();

    if (tid == 0) {
        float a[K], b[K];
#pragma unroll
        for (int i = 0; i < K; ++i) a[i] = smem[i];
#pragma unroll
        for (int i = 0; i < K; ++i) b[i] = smem[K + i];
        merge8(a, b);
#pragma unroll
        for (int i = 0; i < K; ++i) b[i] = smem[2 * K + i];
        merge8(a, b);
#pragma unroll
        for (int i = 0; i < K; ++i) b[i] = smem[3 * K + i];
        merge8(a, b);

        float s = 0.0f;
#pragma unroll
        for (int i = 0; i < K; ++i) s += a[i];
        row_out[row] = 1.0f - s;
    }
}

__global__ __launch_bounds__(BLOCK) void hl_reduce(const float* __restrict__ in,
                                                   float* __restrict__ out, int n) {
    float s = 0.0f;
    for (int i = threadIdx.x; i < n; i += BLOCK) s += in[i];
#pragma unroll
    for (int m = 32; m >= 1; m >>= 1) s += __shfl_xor(s, m, 64);
    __shared__ float sm[BLOCK / 64];
    if ((threadIdx.x & 63) == 0) sm[threadIdx.x >> 6] = s;
    __syncthreads();
    if (threadIdx.x == 0) {
        float r = 0.0f;
#pragma unroll
        for (int i = 0; i < BLOCK / 64; ++i) r += sm[i];
        out[0] = r;
    }
}

extern "C" void kernel_launch(void* const* d_in, const int* in_sizes, int n_in,
                              void* d_out, int out_size, void* d_ws, size_t ws_size,
                              hipStream_t stream) {
    const float* vals = (const float*)d_in[0];
    // d_in[1] is no_selectors == 8 (hardcoded as K).
    float* out = (float*)d_out;

    const int B = in_sizes[0] / C_COLS;  // 16384
    float* row_ws = (float*)d_ws;        // B floats of scratch

    hl_topk_rows<<<B, BLOCK, 0, stream>>>(vals, row_ws);
    hl_reduce<<<1, BLOCK, 0, stream>>>(row_ws, out, B);
}

// Round 2
// 105.012 us; speedup vs baseline: 1.6789x; 1.6789x over previous
//
#include <hip/hip_runtime.h>
#include <hip/hip_bf16.h>
#include <math.h>

// Top-8 per row of [B, 8192] fp32, out = sum over rows of (1 - sum(top8)).
// Kernel 1: one WAVE per row -> d_ws[row] = 1 - sum(top8(row))
// Kernel 2: reduce d_ws[0..B) -> d_out[0]
//
// Branchless top-k via bitonic merges:
//   top8(a ∪ b) for desc-sorted 8-lists a,b is c[i] = max(a[i], b[7-i]),
//   which is bitonic; a 3-stage bitonic merge re-sorts it descending.

#define C_COLS 8192
#define BLOCK 256
#define ROWS_PER_BLOCK 4   // one wave per row
#define K 8

__device__ __forceinline__ void ce(float& a, float& b) {
    // compare-exchange: larger -> a, smaller -> b
    const float hi = fmaxf(a, b);
    const float lo = fminf(a, b);
    a = hi; b = lo;
}

// Bitonic sort (descending) of a bitonic 8-sequence held in c[0..7].
__device__ __forceinline__ void bitonic_sort8_desc(float (&c)[K]) {
    ce(c[0], c[4]); ce(c[1], c[5]); ce(c[2], c[6]); ce(c[3], c[7]);
    ce(c[0], c[2]); ce(c[1], c[3]); ce(c[4], c[6]); ce(c[5], c[7]);
    ce(c[0], c[1]); ce(c[2], c[3]); ce(c[4], c[5]); ce(c[6], c[7]);
}

// t: desc-sorted top-8. o: desc-sorted 8-list. t <- top8(t ∪ o), desc.
__device__ __forceinline__ void merge8(float (&t)[K], const float (&o)[K]) {
    float c[K];
#pragma unroll
    for (int i = 0; i < K; ++i) c[i] = fmaxf(t[i], o[K - 1 - i]);
    bitonic_sort8_desc(c);
#pragma unroll
    for (int i = 0; i < K; ++i) t[i] = c[i];
}

// Merge a desc-sorted 4-list (b0>=b1>=b2>=b3) into desc-sorted top-8 t.
// Equivalent to merge8 with o = [b0,b1,b2,b3,-inf,-inf,-inf,-inf].
__device__ __forceinline__ void merge4into8(float (&t)[K],
                                            float b0, float b1, float b2, float b3) {
    float c[K];
    c[0] = t[0]; c[1] = t[1]; c[2] = t[2]; c[3] = t[3];
    c[4] = fmaxf(t[4], b3);
    c[5] = fmaxf(t[5], b2);
    c[6] = fmaxf(t[6], b1);
    c[7] = fmaxf(t[7], b0);
    bitonic_sort8_desc(c);
#pragma unroll
    for (int i = 0; i < K; ++i) t[i] = c[i];
}

__global__ __launch_bounds__(BLOCK) void hl_topk_rows(const float* __restrict__ vals,
                                                      float* __restrict__ row_out) {
    const int wave = threadIdx.x >> 6;
    const int lane = threadIdx.x & 63;
    const int row  = blockIdx.x * ROWS_PER_BLOCK + wave;

    const float4* rowp = reinterpret_cast<const float4*>(vals + (size_t)row * C_COLS);

    float t[K];
#pragma unroll
    for (int i = 0; i < K; ++i) t[i] = -INFINITY;

    // 8192 floats = 2048 float4 = 32 iterations of 64 lanes. Coalesced:
    // lane i reads float4 at (j*64 + i) -> 1 KiB per wave per instruction.
#pragma unroll 4
    for (int j = 0; j < (C_COLS / 4) / 64; ++j) {
        float4 v = rowp[j * 64 + lane];
        // sort4 descending: v.x >= v.y >= v.z >= v.w
        ce(v.x, v.y); ce(v.z, v.w); ce(v.x, v.z); ce(v.y, v.w); ce(v.y, v.z);
        merge4into8(t, v.x, v.y, v.z, v.w);
    }

    // 64-lane butterfly: every lane ends with the row's top-8 (desc).
#pragma unroll
    for (int m = 1; m < 64; m <<= 1) {
        float o[K];
#pragma unroll
        for (int i = 0; i < K; ++i) o[i] = __shfl_xor(t[i], m, 64);
        merge8(t, o);
    }

    if (lane == 0) {
        float s = 0.0f;
#pragma unroll
        for (int i = 0; i < K; ++i) s += t[i];
        row_out[row] = 1.0f - s;
    }
}

#define RBLOCK 1024

__global__ __launch_bounds__(RBLOCK) void hl_reduce(const float* __restrict__ in,
                                                    float* __restrict__ out, int n) {
    float s = 0.0f;
    for (int i = threadIdx.x; i < n; i += RBLOCK) s += in[i];
#pragma unroll
    for (int m = 32; m >= 1; m >>= 1) s += __shfl_xor(s, m, 64);
    __shared__ float sm[RBLOCK / 64];
    if ((threadIdx.x & 63) == 0) sm[threadIdx.x >> 6] = s;
    __syncthreads();
    if (threadIdx.x == 0) {
        float r = 0.0f;
#pragma unroll
        for (int i = 0; i < RBLOCK / 64; ++i) r += sm[i];
        out[0] = r;
    }
}

extern "C" void kernel_launch(void* const* d_in, const int* in_sizes, int n_in,
                              void* d_out, int out_size, void* d_ws, size_t ws_size,
                              hipStream_t stream) {
    const float* vals = (const float*)d_in[0];
    // d_in[1] is no_selectors == 8 (hardcoded as K).
    float* out = (float*)d_out;

    const int B = in_sizes[0] / C_COLS;  // 16384
    float* row_ws = (float*)d_ws;        // B floats of scratch

    hl_topk_rows<<<B / ROWS_PER_BLOCK, BLOCK, 0, stream>>>(vals, row_ws);
    hl_reduce<<<1, RBLOCK, 0, stream>>>(row_ws, out, B);
}

// Round 3
// 90.382 us; speedup vs baseline: 1.9507x; 1.1619x over previous
//
#include <hip/hip_runtime.h>
#include <hip/hip_bf16.h>
#include <math.h>

// Top-8 per row of [B, 8192] fp32, out = sum over rows of (1 - sum(top8)).
// Kernel 1: one WAVE per row; one partial per BLOCK -> d_ws[blockIdx]
// Kernel 2: reduce 4096 partials -> d_out[0]
//
// Branchless top-k via bitonic merges:
//   top8(a ∪ b) for desc-sorted 8-lists a,b is c[i] = max(a[i], b[7-i]),
//   which is bitonic; a 3-stage bitonic merge re-sorts it descending.

#define C_COLS 8192
#define BLOCK 256
#define ROWS_PER_BLOCK 4   // one wave per row
#define K 8

typedef float f32x4 __attribute__((ext_vector_type(4)));

__device__ __forceinline__ void ce(float& a, float& b) {
    // compare-exchange: larger -> a, smaller -> b
    const float hi = fmaxf(a, b);
    const float lo = fminf(a, b);
    a = hi; b = lo;
}

// Bitonic sort (descending) of a bitonic 8-sequence held in c[0..7].
__device__ __forceinline__ void bitonic_sort8_desc(float (&c)[K]) {
    ce(c[0], c[4]); ce(c[1], c[5]); ce(c[2], c[6]); ce(c[3], c[7]);
    ce(c[0], c[2]); ce(c[1], c[3]); ce(c[4], c[6]); ce(c[5], c[7]);
    ce(c[0], c[1]); ce(c[2], c[3]); ce(c[4], c[5]); ce(c[6], c[7]);
}

// t: desc-sorted top-8. o: desc-sorted 8-list. t <- top8(t ∪ o), desc.
__device__ __forceinline__ void merge8(float (&t)[K], const float (&o)[K]) {
    float c[K];
#pragma unroll
    for (int i = 0; i < K; ++i) c[i] = fmaxf(t[i], o[K - 1 - i]);
    bitonic_sort8_desc(c);
#pragma unroll
    for (int i = 0; i < K; ++i) t[i] = c[i];
}

// Merge a desc-sorted 4-list (b0>=b1>=b2>=b3) into desc-sorted top-8 t.
__device__ __forceinline__ void merge4into8(float (&t)[K],
                                            float b0, float b1, float b2, float b3) {
    float c[K];
    c[0] = t[0]; c[1] = t[1]; c[2] = t[2]; c[3] = t[3];
    c[4] = fmaxf(t[4], b3);
    c[5] = fmaxf(t[5], b2);
    c[6] = fmaxf(t[6], b1);
    c[7] = fmaxf(t[7], b0);
    bitonic_sort8_desc(c);
#pragma unroll
    for (int i = 0; i < K; ++i) t[i] = c[i];
}

__global__ __launch_bounds__(BLOCK) void hl_topk_rows(const float* __restrict__ vals,
                                                      float* __restrict__ block_out) {
    const int wave = threadIdx.x >> 6;
    const int lane = threadIdx.x & 63;
    const int row  = blockIdx.x * ROWS_PER_BLOCK + wave;

    const f32x4* rowp = reinterpret_cast<const f32x4*>(vals + (size_t)row * C_COLS);

    float t[K];
#pragma unroll
    for (int i = 0; i < K; ++i) t[i] = -INFINITY;

    // 8192 floats = 2048 float4 = 32 iterations of 64 lanes; unroll 8 keeps
    // 8 global_load_dwordx4 (nt) in flight per wave.
#pragma unroll 8
    for (int j = 0; j < (C_COLS / 4) / 64; ++j) {
        f32x4 v = __builtin_nontemporal_load(rowp + j * 64 + lane);
        float x = v[0], y = v[1], z = v[2], w = v[3];
        // sort4 descending: x >= y >= z >= w
        ce(x, y); ce(z, w); ce(x, z); ce(y, w); ce(y, z);
        merge4into8(t, x, y, z, w);
    }

    // 64-lane butterfly: every lane ends with the row's top-8 (desc).
#pragma unroll
    for (int m = 1; m < 64; m <<= 1) {
        float o[K];
#pragma unroll
        for (int i = 0; i < K; ++i) o[i] = __shfl_xor(t[i], m, 64);
        merge8(t, o);
    }

    // Per-block partial: sum of (1 - sum(top8)) over the block's 4 rows.
    __shared__ float sm[ROWS_PER_BLOCK];
    if (lane == 0) {
        float s = 0.0f;
#pragma unroll
        for (int i = 0; i < K; ++i) s += t[i];
        sm[wave] = 1.0f - s;
    }
    __syncthreads();
    if (threadIdx.x == 0) {
        float r = 0.0f;
#pragma unroll
        for (int i = 0; i < ROWS_PER_BLOCK; ++i) r += sm[i];
        block_out[blockIdx.x] = r;
    }
}

#define RBLOCK 1024

__global__ __launch_bounds__(RBLOCK) void hl_reduce(const float* __restrict__ in,
                                                    float* __restrict__ out, int n4) {
    // n4 = number of float4 chunks (n/4). For B=16384: 1024 -> 1 iter/thread.
    const f32x4* in4 = reinterpret_cast<const f32x4*>(in);
    float s = 0.0f;
    for (int i = threadIdx.x; i < n4; i += RBLOCK) {
        f32x4 v = in4[i];
        s += (v[0] + v[1]) + (v[2] + v[3]);
    }
#pragma unroll
    for (int m = 32; m >= 1; m >>= 1) s += __shfl_xor(s, m, 64);
    __shared__ float sm[RBLOCK / 64];
    if ((threadIdx.x & 63) == 0) sm[threadIdx.x >> 6] = s;
    __syncthreads();
    if (threadIdx.x == 0) {
        float r = 0.0f;
#pragma unroll
        for (int i = 0; i < RBLOCK / 64; ++i) r += sm[i];
        out[0] = r;
    }
}

extern "C" void kernel_launch(void* const* d_in, const int* in_sizes, int n_in,
                              void* d_out, int out_size, void* d_ws, size_t ws_size,
                              hipStream_t stream) {
    const float* vals = (const float*)d_in[0];
    // d_in[1] is no_selectors == 8 (hardcoded as K).
    float* out = (float*)d_out;

    const int B = in_sizes[0] / C_COLS;       // 16384
    const int nblocks = B / ROWS_PER_BLOCK;   // 4096
    float* part_ws = (float*)d_ws;            // nblocks floats of scratch

    hl_topk_rows<<<nblocks, BLOCK, 0, stream>>>(vals, part_ws);
    hl_reduce<<<1, RBLOCK, 0, stream>>>(part_ws, out, nblocks / 4);
}